// Round 2
// baseline (805.115 us; speedup 1.0000x reference)
//
#include <hip/hip_runtime.h>
#include <hip/hip_bf16.h>

typedef unsigned short ushortT;
typedef unsigned int uintT;

#define B_ 64
#define S_ 512
#define H_ 1024
#define V_ 32000
#define SB_ (S_ * B_)

using short8 = __attribute__((ext_vector_type(8))) short;
using f32x4  = __attribute__((ext_vector_type(4))) float;

__device__ __forceinline__ ushortT f2bf(float f) {
    __hip_bfloat16 h = __float2bfloat16(f);  // RNE
    union { __hip_bfloat16 h; ushortT u; } x;
    x.h = h;
    return x.u;
}
__device__ __forceinline__ float fast_tanh(float x) {
    float e = __expf(2.0f * x);           // inf-safe: +inf -> 1, 0 -> -1
    return 1.0f - 2.0f / (e + 1.0f);
}
__device__ __forceinline__ float fast_sigmoid(float x) {
    return 1.0f / (1.0f + __expf(-x));
}
// convert float4 -> 4 bf16, single 8B LDS store
__device__ __forceinline__ void cvt4_store(ushortT* dst, float4 g) {
    ushort4 o;
    o.x = f2bf(g.x); o.y = f2bf(g.y); o.z = f2bf(g.z); o.w = f2bf(g.w);
    *(ushort4*)dst = o;
}

// ---------------------------------------------------------------------------
// Attention GEMM: E[r][h] = tanh( enc[r]·W2[h] + c[b][h] ), scores[r] += v[h]*E
// r = s*64+b (M=32768), h (N=1024), K=1024. 128x128 tile, BK=64, 4 waves.
// f32 inputs, converted to bf16 during LDS staging; bf16 MFMA; f32 epilogue.
// ---------------------------------------------------------------------------
__global__ __launch_bounds__(256, 2)
void attn_gemm_kernel(const float* __restrict__ enc,    // [SB][H] f32
                      const float* __restrict__ W,      // attn_w_W [H][2H] f32
                      const float* __restrict__ cbias,  // [B][H] f32
                      const float* __restrict__ v,      // [H] f32
                      float*       __restrict__ scores) // [SB] f32 (pre-zeroed, atomic)
{
    __shared__ ushortT sA[128 * 64];
    __shared__ ushortT sB[128 * 64];
    const int t = threadIdx.x;
    const int wave = t >> 6, lane = t & 63;
    const int row0 = blockIdx.x * 128;
    const int col0 = blockIdx.y * 128;
    const int wr = wave >> 1, wc = wave & 1;
    const int lidx = lane & 15, quad = lane >> 4;

    f32x4 acc[4][4] = {};

    for (int k0 = 0; k0 < H_; k0 += 64) {
        __syncthreads();
#pragma unroll
        for (int i = 0; i < 8; ++i) {
            int e = i * 1024 + t * 4;        // element index in 128x64 tile
            int row = e >> 6, col = e & 63;
            float4 ga = *(const float4*)&enc[(size_t)(row0 + row) * H_ + k0 + col];
            cvt4_store(&sA[e], ga);
            float4 gb = *(const float4*)&W[(size_t)(col0 + row) * 2048 + H_ + k0 + col];
            cvt4_store(&sB[e], gb);
        }
        __syncthreads();
#pragma unroll
        for (int kk = 0; kk < 64; kk += 32) {
            const int kb = kk + quad * 8;
            short8 af[4], bfr[4];
#pragma unroll
            for (int i = 0; i < 4; ++i)
                af[i] = *(const short8*)&sA[(wr * 64 + i * 16 + lidx) * 64 + kb];
#pragma unroll
            for (int j = 0; j < 4; ++j)
                bfr[j] = *(const short8*)&sB[(wc * 64 + j * 16 + lidx) * 64 + kb];
#pragma unroll
            for (int i = 0; i < 4; ++i)
#pragma unroll
                for (int j = 0; j < 4; ++j)
                    acc[i][j] = __builtin_amdgcn_mfma_f32_16x16x32_bf16(af[i], bfr[j], acc[i][j], 0, 0, 0);
        }
    }

    // epilogue: tanh(+c), dot with v, reduce cols, atomicAdd per row
    float vv[4];
#pragma unroll
    for (int j = 0; j < 4; ++j)
        vv[j] = v[col0 + wc * 64 + j * 16 + lidx];

#pragma unroll
    for (int i = 0; i < 4; ++i) {
#pragma unroll
        for (int p = 0; p < 4; ++p) {
            int r = row0 + wr * 64 + i * 16 + quad * 4 + p;  // C/D row = quad*4+reg
            int b = r & (B_ - 1);
            float rs = 0.f;
#pragma unroll
            for (int j = 0; j < 4; ++j) {
                int h = col0 + wc * 64 + j * 16 + lidx;      // C/D col = lane&15
                float e = fast_tanh(acc[i][j][p] + cbias[b * H_ + h]);
                rs += vv[j] * e;
            }
            rs += __shfl_xor(rs, 1);
            rs += __shfl_xor(rs, 2);
            rs += __shfl_xor(rs, 4);
            rs += __shfl_xor(rs, 8);
            if (lidx == 0) atomicAdd(&scores[r], rs);
        }
    }
}

// ---------------------------------------------------------------------------
// Skinny-M GEMM: C[m][n] = A[m]·Bt[n] + bias[n], M=64 fixed, BN=64, BK=64.
// A [64][K] f32 (stride strideA), Bt [N][K] f32 (stride strideB), C f32.
// f32 -> bf16 conversion in staging; bf16 MFMA; f32 out.
// ---------------------------------------------------------------------------
__global__ __launch_bounds__(256, 2)
void gemm64_kernel(const float* __restrict__ A,
                   const float* __restrict__ Bt,
                   const float* __restrict__ bias,
                   float* __restrict__ Cout,
                   int K, int strideA, int strideB, int ldc)
{
    __shared__ ushortT sA[64 * 64];
    __shared__ ushortT sB[64 * 64];
    const int t = threadIdx.x;
    const int wave = t >> 6, lane = t & 63;
    const int col0 = blockIdx.x * 64;
    const int lidx = lane & 15, quad = lane >> 4;

    f32x4 acc[4] = {};

    for (int k0 = 0; k0 < K; k0 += 64) {
        __syncthreads();
#pragma unroll
        for (int i = 0; i < 4; ++i) {
            int e = i * 1024 + t * 4;        // element index in 64x64 tile
            int row = e >> 6, col = e & 63;
            float4 ga = *(const float4*)&A[(size_t)row * strideA + k0 + col];
            cvt4_store(&sA[e], ga);
            float4 gb = *(const float4*)&Bt[(size_t)(col0 + row) * strideB + k0 + col];
            cvt4_store(&sB[e], gb);
        }
        __syncthreads();
#pragma unroll
        for (int kk = 0; kk < 64; kk += 32) {
            const int kb = kk + quad * 8;
            short8 bfr = *(const short8*)&sB[(wave * 16 + lidx) * 64 + kb];
#pragma unroll
            for (int i = 0; i < 4; ++i) {
                short8 af = *(const short8*)&sA[(i * 16 + lidx) * 64 + kb];
                acc[i] = __builtin_amdgcn_mfma_f32_16x16x32_bf16(af, bfr, acc[i], 0, 0, 0);
            }
        }
    }

    const int n = col0 + wave * 16 + lidx;
    const float bb = bias[n];
#pragma unroll
    for (int i = 0; i < 4; ++i) {
#pragma unroll
        for (int p = 0; p < 4; ++p) {
            int m = i * 16 + quad * 4 + p;
            Cout[(size_t)m * ldc + n] = acc[i][p] + bb;
        }
    }
}

// ---------------------------------------------------------------------------
// Softmax over s per column b: block = one b, 256 thr, 2 s each.
// ---------------------------------------------------------------------------
__global__ __launch_bounds__(256)
void softmax_kernel(const float* __restrict__ scores, float* __restrict__ wf32,
                    float* __restrict__ wout)
{
    __shared__ float red[256];
    const int b = blockIdx.x, t = threadIdx.x;
    float s0 = scores[t * 64 + b];
    float s1 = scores[(t + 256) * 64 + b];
    red[t] = fmaxf(s0, s1);
    __syncthreads();
    for (int off = 128; off > 0; off >>= 1) {
        if (t < off) red[t] = fmaxf(red[t], red[t + off]);
        __syncthreads();
    }
    float m = red[0];
    __syncthreads();
    float e0 = __expf(s0 - m), e1 = __expf(s1 - m);
    red[t] = e0 + e1;
    __syncthreads();
    for (int off = 128; off > 0; off >>= 1) {
        if (t < off) red[t] += red[t + off];
        __syncthreads();
    }
    float inv = 1.0f / red[0];
    float w0 = e0 * inv, w1 = e1 * inv;
    wf32[t * 64 + b] = w0;
    wf32[(t + 256) * 64 + b] = w1;
    wout[t * 64 + b] = w0;
    wout[(t + 256) * 64 + b] = w1;
}

// ---------------------------------------------------------------------------
// contexts[b][k] = sum_s w[s][b]*enc[s][b][k]. Block = (b, s-chunk of 64).
// ---------------------------------------------------------------------------
__global__ __launch_bounds__(256)
void context_kernel(const float* __restrict__ enc, const float* __restrict__ wf32,
                    float* __restrict__ ctx)
{
    const int b = blockIdx.x & 63, sc = blockIdx.x >> 6;
    const int t = threadIdx.x;
    const int k = t * 4;
    float a0 = 0.f, a1 = 0.f, a2 = 0.f, a3 = 0.f;
    for (int s = sc * 64; s < sc * 64 + 64; ++s) {
        float w = wf32[s * 64 + b];
        float4 u = *(const float4*)&enc[((size_t)s * 64 + b) * H_ + k];
        a0 += w * u.x;
        a1 += w * u.y;
        a2 += w * u.z;
        a3 += w * u.w;
    }
    atomicAdd(&ctx[b * H_ + k + 0], a0);
    atomicAdd(&ctx[b * H_ + k + 1], a1);
    atomicAdd(&ctx[b * H_ + k + 2], a2);
    atomicAdd(&ctx[b * H_ + k + 3], a3);
}

// ---------------------------------------------------------------------------
// x[b][0:1024] = emb[input[b]], x[b][1024:2048] = context[b]. All f32.
// ---------------------------------------------------------------------------
__global__ __launch_bounds__(256)
void xbuild_kernel(const int* __restrict__ inp, const float* __restrict__ emb,
                   const float* __restrict__ ctx, float* __restrict__ x)
{
    const int idx = (blockIdx.x * 256 + threadIdx.x) * 4;
    const int b = idx >> 11, k = idx & 2047;
    float4 o;
    if (k < H_) {
        o = *(const float4*)&emb[(size_t)inp[b] * H_ + k];
    } else {
        o = *(const float4*)&ctx[b * H_ + (k - H_)];
    }
    *(float4*)&x[idx] = o;
}

// ---------------------------------------------------------------------------
// GRU gates: r,z,n -> h_new (f32 to d_out's h_new slot).
// ---------------------------------------------------------------------------
__global__ __launch_bounds__(256)
void gates_kernel(const float* __restrict__ gi, const float* __restrict__ gh,
                  const float* __restrict__ hidden,
                  float* __restrict__ hnew_out)
{
    const int idx = blockIdx.x * 256 + threadIdx.x;  // b*H + h
    const int b = idx >> 10, h = idx & (H_ - 1);
    const float ir = gi[b * 3072 + h];
    const float iz = gi[b * 3072 + H_ + h];
    const float in_ = gi[b * 3072 + 2 * H_ + h];
    const float hr = gh[b * 3072 + h];
    const float hz = gh[b * 3072 + H_ + h];
    const float hn = gh[b * 3072 + 2 * H_ + h];
    float r = fast_sigmoid(ir + hr);
    float z = fast_sigmoid(iz + hz);
    float n = fast_tanh(in_ + r * hn);
    float hp = hidden[idx];
    hnew_out[idx] = (1.0f - z) * n + z * hp;
}

extern "C" void kernel_launch(void* const* d_in, const int* in_sizes, int n_in,
                              void* d_out, int out_size, void* d_ws, size_t ws_size,
                              hipStream_t stream)
{
    const int*   inp      = (const int*)d_in[0];
    const float* hidden   = (const float*)d_in[1];
    const float* enc      = (const float*)d_in[2];
    const float* emb      = (const float*)d_in[3];
    const float* attn_w_W = (const float*)d_in[4];
    const float* attn_w_b = (const float*)d_in[5];
    const float* attn_v_W = (const float*)d_in[6];
    // d_in[7] attn_v_b: scalar added to all scores -> softmax-invariant, drops out.
    const float* gru_Wih  = (const float*)d_in[8];
    const float* gru_Whh  = (const float*)d_in[9];
    const float* gru_bih  = (const float*)d_in[10];
    const float* gru_bhh  = (const float*)d_in[11];
    const float* out_W    = (const float*)d_in[12];
    const float* out_b    = (const float*)d_in[13];

    char* ws = (char*)d_ws;
    float* ws_scores  = (float*)(ws + 0);        // SB f32 (atomic, zeroed)
    float* ws_context = (float*)(ws + 131072);   // B*H f32 (atomic, zeroed)
    float* ws_c       = (float*)(ws + 393216);   // B*H f32
    float* ws_w       = (float*)(ws + 655360);   // SB f32
    float* ws_gi      = (float*)(ws + 786432);   // B*3H f32
    float* ws_gh      = (float*)(ws + 1572864);  // B*3H f32
    float* ws_x       = (float*)(ws + 2359296);  // B*2H f32

    float* out_logits = (float*)d_out;              // [B][V]
    float* out_hnew   = out_logits + (size_t)B_ * V_; // [1][B][H]
    float* out_attnw  = out_hnew + (size_t)B_ * H_;   // [S][B][1]

    // zero the atomic-accumulated regions (ws is poisoned 0xAA before each call)
    hipMemsetAsync(d_ws, 0, 393216, stream);

    // c[b][h] = hidden[b]·W1[h] + attn_w_b[h]
    gemm64_kernel<<<dim3(H_ / 64), 256, 0, stream>>>(
        hidden, attn_w_W, attn_w_b, ws_c, H_, H_, 2 * H_, H_);

    // scores[r] = sum_h v[h]*tanh(enc[r]·W2[h] + c[b][h])
    attn_gemm_kernel<<<dim3(SB_ / 128, H_ / 128), 256, 0, stream>>>(
        enc, attn_w_W, ws_c, attn_v_W, ws_scores);

    softmax_kernel<<<dim3(B_), 256, 0, stream>>>(ws_scores, ws_w, out_attnw);

    context_kernel<<<dim3(B_ * (S_ / 64)), 256, 0, stream>>>(enc, ws_w, ws_context);

    xbuild_kernel<<<dim3(B_ * 2 * H_ / 4 / 256), 256, 0, stream>>>(inp, emb, ws_context, ws_x);

    // gi = x·Wih^T + bih ; gh = hidden·Whh^T + bhh
    gemm64_kernel<<<dim3(3 * H_ / 64), 256, 0, stream>>>(
        ws_x, gru_Wih, gru_bih, ws_gi, 2 * H_, 2 * H_, 2 * H_, 3 * H_);
    gemm64_kernel<<<dim3(3 * H_ / 64), 256, 0, stream>>>(
        hidden, gru_Whh, gru_bhh, ws_gh, H_, H_, H_, 3 * H_);

    gates_kernel<<<dim3(B_ * H_ / 256), 256, 0, stream>>>(
        ws_gi, ws_gh, hidden, out_hnew);

    // logits = h_new·out_W^T + out_b
    gemm64_kernel<<<dim3(V_ / 64), 256, 0, stream>>>(
        out_hnew, out_W, out_b, out_logits, H_, H_, H_, V_);
}

// Round 3
// 599.013 us; speedup vs baseline: 1.3441x; 1.3441x over previous
//
#include <hip/hip_runtime.h>
#include <hip/hip_bf16.h>

typedef unsigned short ushortT;
typedef unsigned int uintT;

#define B_ 64
#define S_ 512
#define H_ 1024
#define V_ 32000
#define SB_ (S_ * B_)

using short8  = __attribute__((ext_vector_type(8))) short;
using ushort8 = __attribute__((ext_vector_type(8))) unsigned short;
using f32x4   = __attribute__((ext_vector_type(4))) float;

__device__ __forceinline__ float bf2f(ushortT u) {
    union { uintT i; float f; } x;
    x.i = ((uintT)u) << 16;
    return x.f;
}
__device__ __forceinline__ ushortT f2bf(float f) {
    __hip_bfloat16 h = __float2bfloat16(f);  // RNE
    union { __hip_bfloat16 h; ushortT u; } x;
    x.h = h;
    return x.u;
}
__device__ __forceinline__ float fast_tanh(float x) {
    float e = __expf(2.0f * x);           // inf-safe: +inf -> 1, 0 -> -1
    return 1.0f - 2.0f / (e + 1.0f);
}
__device__ __forceinline__ float fast_sigmoid(float x) {
    return 1.0f / (1.0f + __expf(-x));
}
__device__ __forceinline__ void cvt4_store(ushortT* dst, float4 g) {
    ushort4 o;
    o.x = f2bf(g.x); o.y = f2bf(g.y); o.z = f2bf(g.z); o.w = f2bf(g.w);
    *(ushort4*)dst = o;
}
// async global->LDS, 16B per lane. LDS dest is wave-uniform base; HW scatters lane*16B.
__device__ __forceinline__ void gl_lds16(const void* gptr, void* ldsptr) {
    __builtin_amdgcn_global_load_lds(
        (__attribute__((address_space(1))) void*)gptr,
        (__attribute__((address_space(3))) void*)ldsptr,
        16, 0, 0);
}

// ---------------------------------------------------------------------------
// Convert f32 -> bf16: enc [SB*H] flat, plus W2 = attn_w_W[:, H:2H] -> dense [H][H].
// ---------------------------------------------------------------------------
__global__ __launch_bounds__(256)
void convert_kernel(const float* __restrict__ enc, const float* __restrict__ W,
                    ushortT* __restrict__ encbf, ushortT* __restrict__ w2bf)
{
    if (blockIdx.x < 16384) {
        size_t e = ((size_t)blockIdx.x * 256 + threadIdx.x) * 8;
        float4 a = *(const float4*)&enc[e];
        float4 b = *(const float4*)&enc[e + 4];
        ushort8 o;
        o[0] = f2bf(a.x); o[1] = f2bf(a.y); o[2] = f2bf(a.z); o[3] = f2bf(a.w);
        o[4] = f2bf(b.x); o[5] = f2bf(b.y); o[6] = f2bf(b.z); o[7] = f2bf(b.w);
        *(ushort8*)&encbf[e] = o;
    } else {
        size_t idx = (((size_t)blockIdx.x - 16384) * 256 + threadIdx.x) * 8;
        int row = (int)(idx >> 10), col = (int)(idx & 1023);
        const float* src = &W[(size_t)row * 2048 + 1024 + col];
        float4 a = *(const float4*)src;
        float4 b = *(const float4*)(src + 4);
        ushort8 o;
        o[0] = f2bf(a.x); o[1] = f2bf(a.y); o[2] = f2bf(a.z); o[3] = f2bf(a.w);
        o[4] = f2bf(b.x); o[5] = f2bf(b.y); o[6] = f2bf(b.z); o[7] = f2bf(b.w);
        *(ushort8*)&w2bf[idx] = o;
    }
}

// ---------------------------------------------------------------------------
// Attention GEMM (bf16 inputs): E = tanh(enc·W2^T + c), scores += v·E.
// M=32768 (r=s*64+b), N=1024, K=1024. 128x128 tile, BK=64, global_load_lds 16B.
// ---------------------------------------------------------------------------
__global__ __launch_bounds__(256, 4)
void attn_gemm_bf16(const ushortT* __restrict__ enc,    // [SB][H] bf16
                    const ushortT* __restrict__ w2,     // [H][H] bf16 dense
                    const float*   __restrict__ cbias,  // [B][H] f32
                    const float*   __restrict__ v,      // [H] f32
                    float*         __restrict__ scores) // [SB] f32 (zeroed, atomic)
{
    __shared__ ushortT sA[128 * 64];
    __shared__ ushortT sB[128 * 64];
    const int t = threadIdx.x;
    const int wave = t >> 6, lane = t & 63;
    const int row0 = blockIdx.x * 128;
    const int col0 = blockIdx.y * 128;
    const int wr = wave >> 1, wc = wave & 1;
    const int lidx = lane & 15, quad = lane >> 4;

    f32x4 acc[4][4] = {};

    for (int k0 = 0; k0 < H_; k0 += 64) {
        __syncthreads();
#pragma unroll
        for (int r = 0; r < 4; ++r) {
            int idx = r * 2048 + wave * 512 + lane * 8;  // elements in 128x64 tile
            int row = idx >> 6, ck = idx & 63;
            gl_lds16(enc + (size_t)(row0 + row) * H_ + k0 + ck, &sA[r * 2048 + wave * 512]);
            gl_lds16(w2 + (size_t)(col0 + row) * H_ + k0 + ck, &sB[r * 2048 + wave * 512]);
        }
        __syncthreads();
#pragma unroll
        for (int kk = 0; kk < 64; kk += 32) {
            const int kb = kk + quad * 8;
            short8 af[4], bfr[4];
#pragma unroll
            for (int i = 0; i < 4; ++i)
                af[i] = *(const short8*)&sA[(wr * 64 + i * 16 + lidx) * 64 + kb];
#pragma unroll
            for (int j = 0; j < 4; ++j)
                bfr[j] = *(const short8*)&sB[(wc * 64 + j * 16 + lidx) * 64 + kb];
#pragma unroll
            for (int i = 0; i < 4; ++i)
#pragma unroll
                for (int j = 0; j < 4; ++j)
                    acc[i][j] = __builtin_amdgcn_mfma_f32_16x16x32_bf16(af[i], bfr[j], acc[i][j], 0, 0, 0);
        }
    }

    float vv[4];
#pragma unroll
    for (int j = 0; j < 4; ++j)
        vv[j] = v[col0 + wc * 64 + j * 16 + lidx];

#pragma unroll
    for (int i = 0; i < 4; ++i) {
#pragma unroll
        for (int p = 0; p < 4; ++p) {
            int r = row0 + wr * 64 + i * 16 + quad * 4 + p;  // C/D row = quad*4+reg
            int b = r & (B_ - 1);
            float rs = 0.f;
#pragma unroll
            for (int j = 0; j < 4; ++j) {
                int h = col0 + wc * 64 + j * 16 + lidx;      // C/D col = lane&15
                float e = fast_tanh(acc[i][j][p] + cbias[b * H_ + h]);
                rs += vv[j] * e;
            }
            rs += __shfl_xor(rs, 1);
            rs += __shfl_xor(rs, 2);
            rs += __shfl_xor(rs, 4);
            rs += __shfl_xor(rs, 8);
            if (lidx == 0) atomicAdd(&scores[r], rs);
        }
    }
}

// ---------------------------------------------------------------------------
// Fallback attention GEMM (f32 inputs, cvt staging) — used if ws too small.
// ---------------------------------------------------------------------------
__global__ __launch_bounds__(256, 4)
void attn_gemm_f32(const float* __restrict__ enc, const float* __restrict__ W,
                   const float* __restrict__ cbias, const float* __restrict__ v,
                   float* __restrict__ scores)
{
    __shared__ ushortT sA[128 * 64];
    __shared__ ushortT sB[128 * 64];
    const int t = threadIdx.x;
    const int wave = t >> 6, lane = t & 63;
    const int row0 = blockIdx.x * 128;
    const int col0 = blockIdx.y * 128;
    const int wr = wave >> 1, wc = wave & 1;
    const int lidx = lane & 15, quad = lane >> 4;

    f32x4 acc[4][4] = {};

    for (int k0 = 0; k0 < H_; k0 += 64) {
        __syncthreads();
#pragma unroll
        for (int i = 0; i < 8; ++i) {
            int e = i * 1024 + t * 4;
            int row = e >> 6, col = e & 63;
            cvt4_store(&sA[e], *(const float4*)&enc[(size_t)(row0 + row) * H_ + k0 + col]);
            cvt4_store(&sB[e], *(const float4*)&W[(size_t)(col0 + row) * 2048 + H_ + k0 + col]);
        }
        __syncthreads();
#pragma unroll
        for (int kk = 0; kk < 64; kk += 32) {
            const int kb = kk + quad * 8;
            short8 af[4], bfr[4];
#pragma unroll
            for (int i = 0; i < 4; ++i)
                af[i] = *(const short8*)&sA[(wr * 64 + i * 16 + lidx) * 64 + kb];
#pragma unroll
            for (int j = 0; j < 4; ++j)
                bfr[j] = *(const short8*)&sB[(wc * 64 + j * 16 + lidx) * 64 + kb];
#pragma unroll
            for (int i = 0; i < 4; ++i)
#pragma unroll
                for (int j = 0; j < 4; ++j)
                    acc[i][j] = __builtin_amdgcn_mfma_f32_16x16x32_bf16(af[i], bfr[j], acc[i][j], 0, 0, 0);
        }
    }

    float vv[4];
#pragma unroll
    for (int j = 0; j < 4; ++j)
        vv[j] = v[col0 + wc * 64 + j * 16 + lidx];
#pragma unroll
    for (int i = 0; i < 4; ++i) {
#pragma unroll
        for (int p = 0; p < 4; ++p) {
            int r = row0 + wr * 64 + i * 16 + quad * 4 + p;
            int b = r & (B_ - 1);
            float rs = 0.f;
#pragma unroll
            for (int j = 0; j < 4; ++j) {
                int h = col0 + wc * 64 + j * 16 + lidx;
                rs += vv[j] * fast_tanh(acc[i][j][p] + cbias[b * H_ + h]);
            }
            rs += __shfl_xor(rs, 1);
            rs += __shfl_xor(rs, 2);
            rs += __shfl_xor(rs, 4);
            rs += __shfl_xor(rs, 8);
            if (lidx == 0) atomicAdd(&scores[r], rs);
        }
    }
}

// ---------------------------------------------------------------------------
// Skinny-M GEMM with split-K: C[m][n] = A[m]·Bt[n] + bias[n], M=64, BN=64, BK=64.
// grid = (N/64, KSPLIT). Kc = K/KSPLIT. ATOMIC: accumulate with atomicAdd
// (Cout pre-zeroed), bias added by the ky==0 block only.
// ---------------------------------------------------------------------------
template <bool ATOMIC>
__global__ __launch_bounds__(256, 4)
void gemm64_kernel(const float* __restrict__ A,
                   const float* __restrict__ Bt,
                   const float* __restrict__ bias,
                   float* __restrict__ Cout,
                   int Kc, int strideA, int strideB, int ldc)
{
    __shared__ ushortT sA[64 * 64];
    __shared__ ushortT sB[64 * 64];
    const int t = threadIdx.x;
    const int wave = t >> 6, lane = t & 63;
    const int col0 = blockIdx.x * 64;
    const int kbase = blockIdx.y * Kc;
    const int lidx = lane & 15, quad = lane >> 4;

    f32x4 acc[4] = {};

    for (int k0 = kbase; k0 < kbase + Kc; k0 += 64) {
        __syncthreads();
#pragma unroll
        for (int i = 0; i < 4; ++i) {
            int e = i * 1024 + t * 4;
            int row = e >> 6, col = e & 63;
            cvt4_store(&sA[e], *(const float4*)&A[(size_t)row * strideA + k0 + col]);
            cvt4_store(&sB[e], *(const float4*)&Bt[(size_t)(col0 + row) * strideB + k0 + col]);
        }
        __syncthreads();
#pragma unroll
        for (int kk = 0; kk < 64; kk += 32) {
            const int kb = kk + quad * 8;
            short8 bfr = *(const short8*)&sB[(wave * 16 + lidx) * 64 + kb];
#pragma unroll
            for (int i = 0; i < 4; ++i) {
                short8 af = *(const short8*)&sA[(i * 16 + lidx) * 64 + kb];
                acc[i] = __builtin_amdgcn_mfma_f32_16x16x32_bf16(af, bfr, acc[i], 0, 0, 0);
            }
        }
    }

    const int n = col0 + wave * 16 + lidx;
    const float bb = (!ATOMIC || blockIdx.y == 0) ? bias[n] : 0.0f;
#pragma unroll
    for (int i = 0; i < 4; ++i) {
#pragma unroll
        for (int p = 0; p < 4; ++p) {
            int m = i * 16 + quad * 4 + p;
            if (ATOMIC)
                atomicAdd(&Cout[(size_t)m * ldc + n], acc[i][p] + bb);
            else
                Cout[(size_t)m * ldc + n] = acc[i][p] + bb;
        }
    }
}

// ---------------------------------------------------------------------------
// Softmax over s per column b.
// ---------------------------------------------------------------------------
__global__ __launch_bounds__(256)
void softmax_kernel(const float* __restrict__ scores, float* __restrict__ wf32,
                    float* __restrict__ wout)
{
    __shared__ float red[256];
    const int b = blockIdx.x, t = threadIdx.x;
    float s0 = scores[t * 64 + b];
    float s1 = scores[(t + 256) * 64 + b];
    red[t] = fmaxf(s0, s1);
    __syncthreads();
    for (int off = 128; off > 0; off >>= 1) {
        if (t < off) red[t] = fmaxf(red[t], red[t + off]);
        __syncthreads();
    }
    float m = red[0];
    __syncthreads();
    float e0 = __expf(s0 - m), e1 = __expf(s1 - m);
    red[t] = e0 + e1;
    __syncthreads();
    for (int off = 128; off > 0; off >>= 1) {
        if (t < off) red[t] += red[t + off];
        __syncthreads();
    }
    float inv = 1.0f / red[0];
    float w0 = e0 * inv, w1 = e1 * inv;
    wf32[t * 64 + b] = w0;
    wf32[(t + 256) * 64 + b] = w1;
    wout[t * 64 + b] = w0;
    wout[(t + 256) * 64 + b] = w1;
}

// ---------------------------------------------------------------------------
// contexts[b][k] = sum_s w[s][b]*enc[s][b][k] — bf16 enc variant (L3-hot).
// ---------------------------------------------------------------------------
__global__ __launch_bounds__(256)
void context_bf16(const ushortT* __restrict__ enc, const float* __restrict__ wf32,
                  float* __restrict__ ctx)
{
    const int b = blockIdx.x & 63, sc = blockIdx.x >> 6;
    const int t = threadIdx.x;
    const int k = t * 4;
    float a0 = 0.f, a1 = 0.f, a2 = 0.f, a3 = 0.f;
    for (int s = sc * 64; s < sc * 64 + 64; ++s) {
        float w = wf32[s * 64 + b];
        ushort4 u = *(const ushort4*)&enc[((size_t)s * 64 + b) * H_ + k];
        a0 += w * bf2f(u.x);
        a1 += w * bf2f(u.y);
        a2 += w * bf2f(u.z);
        a3 += w * bf2f(u.w);
    }
    atomicAdd(&ctx[b * H_ + k + 0], a0);
    atomicAdd(&ctx[b * H_ + k + 1], a1);
    atomicAdd(&ctx[b * H_ + k + 2], a2);
    atomicAdd(&ctx[b * H_ + k + 3], a3);
}

__global__ __launch_bounds__(256)
void context_f32(const float* __restrict__ enc, const float* __restrict__ wf32,
                 float* __restrict__ ctx)
{
    const int b = blockIdx.x & 63, sc = blockIdx.x >> 6;
    const int t = threadIdx.x;
    const int k = t * 4;
    float a0 = 0.f, a1 = 0.f, a2 = 0.f, a3 = 0.f;
    for (int s = sc * 64; s < sc * 64 + 64; ++s) {
        float w = wf32[s * 64 + b];
        float4 u = *(const float4*)&enc[((size_t)s * 64 + b) * H_ + k];
        a0 += w * u.x; a1 += w * u.y; a2 += w * u.z; a3 += w * u.w;
    }
    atomicAdd(&ctx[b * H_ + k + 0], a0);
    atomicAdd(&ctx[b * H_ + k + 1], a1);
    atomicAdd(&ctx[b * H_ + k + 2], a2);
    atomicAdd(&ctx[b * H_ + k + 3], a3);
}

// ---------------------------------------------------------------------------
// x[b][0:1024] = emb[input[b]], x[b][1024:2048] = context[b].
// ---------------------------------------------------------------------------
__global__ __launch_bounds__(256)
void xbuild_kernel(const int* __restrict__ inp, const float* __restrict__ emb,
                   const float* __restrict__ ctx, float* __restrict__ x)
{
    const int idx = (blockIdx.x * 256 + threadIdx.x) * 4;
    const int b = idx >> 11, k = idx & 2047;
    float4 o;
    if (k < H_) {
        o = *(const float4*)&emb[(size_t)inp[b] * H_ + k];
    } else {
        o = *(const float4*)&ctx[b * H_ + (k - H_)];
    }
    *(float4*)&x[idx] = o;
}

// ---------------------------------------------------------------------------
// GRU gates -> h_new (f32).
// ---------------------------------------------------------------------------
__global__ __launch_bounds__(256)
void gates_kernel(const float* __restrict__ gi, const float* __restrict__ gh,
                  const float* __restrict__ hidden,
                  float* __restrict__ hnew_out)
{
    const int idx = blockIdx.x * 256 + threadIdx.x;
    const int b = idx >> 10, h = idx & (H_ - 1);
    const float ir = gi[b * 3072 + h];
    const float iz = gi[b * 3072 + H_ + h];
    const float in_ = gi[b * 3072 + 2 * H_ + h];
    const float hr = gh[b * 3072 + h];
    const float hz = gh[b * 3072 + H_ + h];
    const float hn = gh[b * 3072 + 2 * H_ + h];
    float r = fast_sigmoid(ir + hr);
    float z = fast_sigmoid(iz + hz);
    float n = fast_tanh(in_ + r * hn);
    hnew_out[idx] = (1.0f - z) * n + z * hidden[idx];
}

extern "C" void kernel_launch(void* const* d_in, const int* in_sizes, int n_in,
                              void* d_out, int out_size, void* d_ws, size_t ws_size,
                              hipStream_t stream)
{
    const int*   inp      = (const int*)d_in[0];
    const float* hidden   = (const float*)d_in[1];
    const float* enc      = (const float*)d_in[2];
    const float* emb      = (const float*)d_in[3];
    const float* attn_w_W = (const float*)d_in[4];
    const float* attn_w_b = (const float*)d_in[5];
    const float* attn_v_W = (const float*)d_in[6];
    // d_in[7] attn_v_b: uniform score shift -> softmax-invariant, drops out.
    const float* gru_Wih  = (const float*)d_in[8];
    const float* gru_Whh  = (const float*)d_in[9];
    const float* gru_bih  = (const float*)d_in[10];
    const float* gru_bhh  = (const float*)d_in[11];
    const float* out_W    = (const float*)d_in[12];
    const float* out_b    = (const float*)d_in[13];

    char* ws = (char*)d_ws;
    float*   ws_scores  = (float*)(ws + 0);        // SB f32 (atomic)
    float*   ws_context = (float*)(ws + 131072);   // B*H f32 (atomic)
    float*   ws_c       = (float*)(ws + 393216);   // B*H f32 (atomic, split-K)
    float*   ws_gi      = (float*)(ws + 655360);   // B*3H f32 (atomic, split-K)
    float*   ws_gh      = (float*)(ws + 1441792);  // B*3H f32 (atomic, split-K)
    float*   ws_w       = (float*)(ws + 2228224);  // SB f32
    float*   ws_x       = (float*)(ws + 2359296);  // B*2H f32
    ushortT* ws_encbf   = (ushortT*)(ws + 2883584);  // SB*H bf16 (64 MB)
    ushortT* ws_w2bf    = (ushortT*)(ws + 69992448); // H*H bf16 (2 MB)
    const size_t WS_NEED = 72089600;
    const bool bf16_path = (ws_size >= WS_NEED);

    float* out_logits = (float*)d_out;                // [B][V]
    float* out_hnew   = out_logits + (size_t)B_ * V_; // [1][B][H]
    float* out_attnw  = out_hnew + (size_t)B_ * H_;   // [S][B][1]

    // zero the atomic-accumulated regions (ws is poisoned 0xAA before each call)
    hipMemsetAsync(d_ws, 0, 2228224, stream);

    // c[b][h] = hidden[b]·W1[h] + attn_w_b[h]  (split-K x4: 64 blocks)
    gemm64_kernel<true><<<dim3(H_ / 64, 4), 256, 0, stream>>>(
        hidden, attn_w_W, attn_w_b, ws_c, H_ / 4, H_, 2 * H_, H_);

    if (bf16_path) {
        convert_kernel<<<dim3(16384 + 512), 256, 0, stream>>>(enc, attn_w_W, ws_encbf, ws_w2bf);
        attn_gemm_bf16<<<dim3(SB_ / 128, H_ / 128), 256, 0, stream>>>(
            ws_encbf, ws_w2bf, ws_c, attn_v_W, ws_scores);
    } else {
        attn_gemm_f32<<<dim3(SB_ / 128, H_ / 128), 256, 0, stream>>>(
            enc, attn_w_W, ws_c, attn_v_W, ws_scores);
    }

    softmax_kernel<<<dim3(B_), 256, 0, stream>>>(ws_scores, ws_w, out_attnw);

    if (bf16_path)
        context_bf16<<<dim3(B_ * (S_ / 64)), 256, 0, stream>>>(ws_encbf, ws_w, ws_context);
    else
        context_f32<<<dim3(B_ * (S_ / 64)), 256, 0, stream>>>(enc, ws_w, ws_context);

    xbuild_kernel<<<dim3(B_ * 2 * H_ / 4 / 256), 256, 0, stream>>>(inp, emb, ws_context, ws_x);

    // gi = x·Wih^T + bih (K=2048, split x4); gh = hidden·Whh^T + bhh (K=1024, split x4)
    gemm64_kernel<true><<<dim3(3 * H_ / 64, 4), 256, 0, stream>>>(
        ws_x, gru_Wih, gru_bih, ws_gi, 2 * H_ / 4, 2 * H_, 2 * H_, 3 * H_);
    gemm64_kernel<true><<<dim3(3 * H_ / 64, 4), 256, 0, stream>>>(
        hidden, gru_Whh, gru_bhh, ws_gh, H_ / 4, H_, H_, 3 * H_);

    gates_kernel<<<dim3(B_ * H_ / 256), 256, 0, stream>>>(
        ws_gi, ws_gh, hidden, out_hnew);

    // logits = h_new·out_W^T + out_b  (500 blocks, no split)
    gemm64_kernel<false><<<dim3(V_ / 64, 1), 256, 0, stream>>>(
        out_hnew, out_W, out_b, out_logits, H_, H_, H_, V_);
}